// Round 1
// 209.522 us; speedup vs baseline: 1.0567x; 1.0567x over previous
//
#include <hip/hip_runtime.h>
#include <math.h>

// Problem constants: n=2, c=256, t=2, h=64, w=64; HB=WB=16, bn_h=bn_w=4;
// NHEAD=8, d=32. Stage1: L1=32 tokens x B1=512 batch. Stage2: L2=512 x B2=32.
// Token id m1 = l1*512 + b1, l1=(t*4+bh)*4+bw, b1=n*256+i*16+j.
// Token id m2 = l2*32 + b2,  l2=t*256+i*16+j,  b2=n*16+bh*4+bw.
// R11 = R10 with the stage-1 tail fused: attn1 now also does the out-proj
// (O1 @ wl_out^T + bias), the m1->m2 permutation and the +pos fold, writing
// X2 and V2in directly. Removes gemm_out1 + perm12 kernels and the O1/V1o
// round trips (~56 MB intermediate traffic, 2 launches). LDS is a union:
// attn arrays (37.4 KB) overlaid with O1s[32][256] + Ws[256][64] (49.2 KB);
// O-frags are held in registers across both heads and spilled to LDS (m97
// XOR-swizzle) only after a barrier, so the overlay cannot clobber live data.

#define SCALE_D32 0.17677669529663687f       // 1/sqrt(32)
#define EXP2_SCALE 0.25508680987930193f      // SCALE_D32 * log2(e)
#define GLOBAL_AS __attribute__((address_space(1)))
#define LDS_AS __attribute__((address_space(3)))

typedef short short8 __attribute__((ext_vector_type(8)));   // 8 bf16 = 16B
typedef short short4v __attribute__((ext_vector_type(4)));  // 4 bf16 = 8B
typedef short short2v __attribute__((ext_vector_type(2)));  // 2 bf16 = 4B
typedef float floatx4 __attribute__((ext_vector_type(4)));  // MFMA C/D frag

__device__ __forceinline__ short f2bf(float f) {
  union { float f; unsigned u; } x;
  x.f = f;
  unsigned r = x.u + 0x7fffu + ((x.u >> 16) & 1u);  // RNE
  return (short)(r >> 16);
}
__device__ __forceinline__ float bf2f(short s) {
  union { unsigned u; float f; } x;
  x.u = ((unsigned)(unsigned short)s) << 16;
  return x.f;
}

// physical index into the swizzled O1s[32][256] tile (matches gemm_tri's
// As layout per 64-k-block: chunk' = chunk ^ (row&7), 8-short granularity)
__device__ __forceinline__ int o1s_phys(int q, int ch) {
  return q * 256 + (ch & ~63) + ((((ch >> 3) & 7) ^ (q & 7)) << 3) + (ch & 7);
}

// ---- pack: [n,c,t,h,w] fp32 -> token-major [16384,256] bf16; + weight cvt --
__global__ __launch_bounds__(256) void pack_kernel(
    const float* __restrict__ q, const float* __restrict__ k,
    const float* __restrict__ v, const float* __restrict__ pos,
    short* __restrict__ Xp, short* __restrict__ Xq,
    short* __restrict__ Xk, short* __restrict__ Xv,
    const float* __restrict__ wl_in, const float* __restrict__ wl_out,
    const float* __restrict__ ws_in, const float* __restrict__ ws_out,
    short* __restrict__ wbf) {
  __shared__ float tP[64][65];
  __shared__ float tX[64][65];
  int b = blockIdx.x;
  int cb = b & 3;
  int h  = (b >> 2) & 63;
  int nt = b >> 8;
  int n = nt >> 1, t = nt & 1;
  int c0 = cb * 64;
  int bh = h >> 4, ii = h & 15;
  long inbase = (long)n * 2097152 + (long)t * 4096 + (long)h * 64;
  int tx = threadIdx.x & 63;
  int ty = threadIdx.x >> 6;  // 0..3

  for (int cc = ty; cc < 64; cc += 4) {
    long a = inbase + (long)(c0 + cc) * 8192 + tx;
    tP[cc][tx] = pos[a];
    tX[cc][tx] = q[a];
  }
  __syncthreads();
  for (int ww = ty; ww < 64; ww += 4) {
    int bw = ww >> 4, j = ww & 15;
    int m1 = (((t * 4 + bh) * 4 + bw) * 512) + n * 256 + ii * 16 + j;
    long o = (long)m1 * 256 + c0 + tx;
    float pv = tP[tx][ww];
    Xp[o] = f2bf(pv);
    Xq[o] = f2bf(tX[tx][ww] + pv);
  }
  __syncthreads();
  for (int cc = ty; cc < 64; cc += 4) {
    long a = inbase + (long)(c0 + cc) * 8192 + tx;
    tX[cc][tx] = k[a];
  }
  __syncthreads();
  for (int ww = ty; ww < 64; ww += 4) {
    int bw = ww >> 4, j = ww & 15;
    int m1 = (((t * 4 + bh) * 4 + bw) * 512) + n * 256 + ii * 16 + j;
    long o = (long)m1 * 256 + c0 + tx;
    Xk[o] = f2bf(tX[tx][ww] + tP[tx][ww]);
  }
  __syncthreads();
  for (int cc = ty; cc < 64; cc += 4) {
    long a = inbase + (long)(c0 + cc) * 8192 + tx;
    tX[cc][tx] = v[a];
  }
  __syncthreads();
  for (int ww = ty; ww < 64; ww += 4) {
    int bw = ww >> 4, j = ww & 15;
    int m1 = (((t * 4 + bh) * 4 + bw) * 512) + n * 256 + ii * 16 + j;
    long o = (long)m1 * 256 + c0 + tx;
    Xv[o] = f2bf(tX[tx][ww]);
  }
  // weight convert tail: 1024 blocks x 256 threads x 2 floats = 524288
  int idx = (blockIdx.x * 256 + threadIdx.x) * 2;
  const float* wp;
  if (idx < 196608) wp = wl_in + idx;
  else if (idx < 262144) wp = wl_out + (idx - 196608);
  else if (idx < 458752) wp = ws_in + (idx - 262144);
  else wp = ws_out + (idx - 458752);
  float2 wv = *(const float2*)wp;
  wbf[idx] = f2bf(wv.x);
  wbf[idx + 1] = f2bf(wv.y);
}

// ------- m97-style bf16 TN GEMM triple: C_z = A_z @ W_z^T + b_z -------------
// Tile 128x64, BK=64, global_load_lds 16B staging, XOR swizzle pc=c^(row&7).
template <bool OUT32>
__global__ __launch_bounds__(256) void gemm_tri(
    const short* __restrict__ A0, const short* __restrict__ A1,
    const short* __restrict__ A2, const short* __restrict__ W0,
    const float* __restrict__ bias0, void* __restrict__ C0,
    void* __restrict__ C1, void* __restrict__ C2) {
  __shared__ short As[128 * 64];  // 16 KB
  __shared__ short Ws[64 * 64];   //  8 KB
  int z = blockIdx.z;
  const short* A = (z == 0) ? A0 : ((z == 1) ? A1 : A2);
  const short* Wb = W0 + z * 65536;
  const float* bias = bias0 + z * 256;
  void* Csel = (z == 0) ? C0 : ((z == 1) ? C1 : C2);
  int m0 = blockIdx.x * 128;
  int n0 = blockIdx.y * 64;
  int tid = threadIdx.x;
  int lane = tid & 63, wave = tid >> 6;
  int wm = wave >> 1, wn = wave & 1;
  int l15 = lane & 15, quad = lane >> 4;
  int x7 = l15 & 7;
  int rsub = lane >> 3;   // 0..7: row within 8-row staging chunk
  int csub = lane & 7;    // logical col16 before swizzle

  floatx4 acc[4][2];
#pragma unroll
  for (int mt = 0; mt < 4; ++mt)
#pragma unroll
    for (int nt = 0; nt < 2; ++nt) acc[mt][nt] = (floatx4)(0.f);

  for (int kb = 0; kb < 4; ++kb) {
    int k0 = kb * 64;
    if (kb) __syncthreads();
#pragma unroll
    for (int j = 0; j < 4; ++j) {
      int r0 = (wave * 4 + j) * 8;
      int row = r0 + rsub;
      int c = csub ^ (row & 7);
      const short* gp = A + (long)(m0 + row) * 256 + k0 + c * 8;
      short* lp = &As[r0 * 64 + lane * 8];
      __builtin_amdgcn_global_load_lds((const GLOBAL_AS void*)gp,
                                       (LDS_AS void*)lp, 16, 0, 0);
    }
#pragma unroll
    for (int j = 0; j < 2; ++j) {
      int r0 = (wave * 2 + j) * 8;
      int row = r0 + rsub;
      int c = csub ^ (row & 7);
      const short* gp = Wb + (long)(n0 + row) * 256 + k0 + c * 8;
      short* lp = &Ws[r0 * 64 + lane * 8];
      __builtin_amdgcn_global_load_lds((const GLOBAL_AS void*)gp,
                                       (LDS_AS void*)lp, 16, 0, 0);
    }
    __syncthreads();
#pragma unroll
    for (int ks = 0; ks < 2; ++ks) {
      int pc = (ks * 4 + quad) ^ x7;
      short8 af[4], bfr[2];
#pragma unroll
      for (int mt = 0; mt < 4; ++mt) {
        int row = wm * 64 + mt * 16 + l15;
        af[mt] = *(const short8*)&As[row * 64 + pc * 8];
      }
#pragma unroll
      for (int nt = 0; nt < 2; ++nt) {
        int row = wn * 32 + nt * 16 + l15;
        bfr[nt] = *(const short8*)&Ws[row * 64 + pc * 8];
      }
#pragma unroll
      for (int mt = 0; mt < 4; ++mt)
#pragma unroll
        for (int nt = 0; nt < 2; ++nt)
          acc[mt][nt] = __builtin_amdgcn_mfma_f32_16x16x32_bf16(
              af[mt], bfr[nt], acc[mt][nt], 0, 0, 0);
    }
  }
  float bia0 = bias[n0 + wn * 32 + l15];
  float bia1 = bias[n0 + wn * 32 + 16 + l15];
#pragma unroll
  for (int mt = 0; mt < 4; ++mt) {
#pragma unroll
    for (int r = 0; r < 4; ++r) {
      int row = m0 + wm * 64 + mt * 16 + quad * 4 + r;
      long base = (long)row * 256 + n0 + wn * 32 + l15;
      if (OUT32) {
        float* C = (float*)Csel;
        C[base] = acc[mt][0][r] + bia0;
        C[base + 16] = acc[mt][1][r] + bia1;
      } else {
        short* C = (short*)Csel;
        C[base] = f2bf(acc[mt][0][r] + bia0);
        C[base + 16] = f2bf(acc[mt][1][r] + bia1);
      }
    }
  }
}

// ---- stage-1 attention + out-proj + perm + pos, fully fused ----------------
// One block (4 waves) per b1. Phase 1 = R10 attn1 (verified math), but O
// fragments stay in registers. Phase 2: spill normalized O tile to swizzled
// LDS O1s[32][256], GEMM against wl_out (Ws[256][64] staged per 64-k-block
// via global_load_lds, identical swizzle/read pattern to gemm_tri), epilogue
// writes X2 = C+bias+pos and V2in = C+bias at permuted rows m2(q,b1).
__global__ __launch_bounds__(256) void attn1_fused(
    const short* __restrict__ Q1, const short* __restrict__ K1,
    const short* __restrict__ V1, const short* __restrict__ Xp,
    const short* __restrict__ Wo, const float* __restrict__ bias,
    short* __restrict__ X2, short* __restrict__ V2in) {
  __shared__ union {
    struct {                      // phase 1 (attention): 37376 B
      short Vs[32][264];          // [key][c] (all heads), +8 pad (528B rows)
      short Vt[4][32][40];        // per-wave [d][pi2(key)], 80B rows
      short Pw[4][32][40];        // per-wave [q][pi2(key)], 80B rows
    } a;
    struct {                      // phase 2 (out-proj GEMM): 49152 B
      short O1s[32 * 256];        // swizzled O tile (bf16)
      short Ws[256 * 64];         // W k-block, swizzled
    } g;
  } u;
  int b1 = blockIdx.x;
  int tid = threadIdx.x;
  int wave = tid >> 6, lane = tid & 63;
  int l15 = lane & 15, quad = lane >> 4;
  int x7 = l15 & 7;
  int rsub = lane >> 3;
  int csub = lane & 7;

  // ---- phase 1: stage V (full 32x256 tile, 4 passes) ----
#pragma unroll
  for (int p = 0; p < 4; ++p) {
    int idx = p * 256 + tid;       // 0..1023
    int row = idx >> 5;            // 0..31
    int c8 = idx & 31;             // 0..31 (short8 chunk within row)
    *(short8*)&u.a.Vs[row][c8 * 8] =
        *(const short8*)(V1 + ((long)row * 512 + b1) * 256 + c8 * 8);
  }
  __syncthreads();

  int key = lane & 31;
  int dh = (lane >> 5) * 16;                 // 0 or 16
  int pc2 = 2 * (key & 15) + (key >> 4);     // pi2(key)

  floatx4 oacc[2][4];    // [h2][o00,o01,o10,o11]
  float lsum[2][2][4];   // [h2][li0/li1][r]

#pragma unroll
  for (int h2 = 0; h2 < 2; ++h2) {
    int hh = wave * 2 + h2;
    // Q/K fragments direct from global: m=l15(+16), k=d=quad*8+j
    long fbase = ((long)l15 * 512 + b1) * 256 + hh * 32 + quad * 8;
    short8 qf0 = *(const short8*)(Q1 + fbase);
    short8 qf1 = *(const short8*)(Q1 + fbase + 16 * 512 * 256);
    short8 kf0 = *(const short8*)(K1 + fbase);
    short8 kf1 = *(const short8*)(K1 + fbase + 16 * 512 * 256);
    // V^T for this head: Vt[d][pi2(key)]; lanes 0-31: d 0..15, 32-63: 16..31
    short8 v0 = *(const short8*)&u.a.Vs[key][hh * 32 + dh];
    short8 v1 = *(const short8*)&u.a.Vs[key][hh * 32 + dh + 8];
#pragma unroll
    for (int j = 0; j < 8; ++j) {
      u.a.Vt[wave][dh + j][pc2] = v0[j];
      u.a.Vt[wave][dh + 8 + j][pc2] = v1[j];
    }
    // S = Q K^T (4 tiles)
    floatx4 s00 = __builtin_amdgcn_mfma_f32_16x16x32_bf16(qf0, kf0, (floatx4)(0.f), 0, 0, 0);
    floatx4 s01 = __builtin_amdgcn_mfma_f32_16x16x32_bf16(qf0, kf1, (floatx4)(0.f), 0, 0, 0);
    floatx4 s10 = __builtin_amdgcn_mfma_f32_16x16x32_bf16(qf1, kf0, (floatx4)(0.f), 0, 0, 0);
    floatx4 s11 = __builtin_amdgcn_mfma_f32_16x16x32_bf16(qf1, kf1, (floatx4)(0.f), 0, 0, 0);
    // no-max softmax; P[q][pi2(k)]: key tiles j=0,1 -> cols 2*l15, 2*l15+1
    float li0[4], li1[4];
#pragma unroll
    for (int r = 0; r < 4; ++r) {
      float p00 = __builtin_amdgcn_exp2f(s00[r] * EXP2_SCALE);
      float p01 = __builtin_amdgcn_exp2f(s01[r] * EXP2_SCALE);
      float p10 = __builtin_amdgcn_exp2f(s10[r] * EXP2_SCALE);
      float p11 = __builtin_amdgcn_exp2f(s11[r] * EXP2_SCALE);
      li0[r] = p00 + p01;
      li1[r] = p10 + p11;
      short2v pa, pb;
      pa.x = f2bf(p00); pa.y = f2bf(p01);
      pb.x = f2bf(p10); pb.y = f2bf(p11);
      *(short2v*)&u.a.Pw[wave][quad * 4 + r][2 * l15] = pa;
      *(short2v*)&u.a.Pw[wave][16 + quad * 4 + r][2 * l15] = pb;
    }
#pragma unroll
    for (int r = 0; r < 4; ++r) {
      li0[r] += __shfl_xor(li0[r], 1, 64);
      li0[r] += __shfl_xor(li0[r], 2, 64);
      li0[r] += __shfl_xor(li0[r], 4, 64);
      li0[r] += __shfl_xor(li0[r], 8, 64);
      li1[r] += __shfl_xor(li1[r], 1, 64);
      li1[r] += __shfl_xor(li1[r], 2, 64);
      li1[r] += __shfl_xor(li1[r], 4, 64);
      li1[r] += __shfl_xor(li1[r], 8, 64);
      lsum[h2][0][r] = li0[r];
      lsum[h2][1][r] = li1[r];
    }
    // PV: O[32q][32d] = P[32q][32k] V[32k][32d] (k pi2-ordered both sides)
    short8 pf0 = *(const short8*)&u.a.Pw[wave][l15][quad * 8];
    short8 pf1 = *(const short8*)&u.a.Pw[wave][16 + l15][quad * 8];
    short8 vt0 = *(const short8*)&u.a.Vt[wave][l15][quad * 8];
    short8 vt1 = *(const short8*)&u.a.Vt[wave][16 + l15][quad * 8];
    oacc[h2][0] = __builtin_amdgcn_mfma_f32_16x16x32_bf16(pf0, vt0, (floatx4)(0.f), 0, 0, 0);
    oacc[h2][1] = __builtin_amdgcn_mfma_f32_16x16x32_bf16(pf0, vt1, (floatx4)(0.f), 0, 0, 0);
    oacc[h2][2] = __builtin_amdgcn_mfma_f32_16x16x32_bf16(pf1, vt0, (floatx4)(0.f), 0, 0, 0);
    oacc[h2][3] = __builtin_amdgcn_mfma_f32_16x16x32_bf16(pf1, vt1, (floatx4)(0.f), 0, 0, 0);
  }

  // all attn LDS reads done before O1s overlays Vs
  __syncthreads();

  // ---- spill normalized O tile to swizzled LDS (bf16, same as old O1) ----
#pragma unroll
  for (int h2 = 0; h2 < 2; ++h2) {
    int hh = wave * 2 + h2;
    int cA = hh * 32 + l15;
    int cB = cA + 16;
#pragma unroll
    for (int r = 0; r < 4; ++r) {
      float inv0 = 1.f / lsum[h2][0][r];
      float inv1 = 1.f / lsum[h2][1][r];
      int qa = quad * 4 + r, qb = 16 + quad * 4 + r;
      u.g.O1s[o1s_phys(qa, cA)] = f2bf(oacc[h2][0][r] * inv0);
      u.g.O1s[o1s_phys(qa, cB)] = f2bf(oacc[h2][1][r] * inv0);
      u.g.O1s[o1s_phys(qb, cA)] = f2bf(oacc[h2][2][r] * inv1);
      u.g.O1s[o1s_phys(qb, cB)] = f2bf(oacc[h2][3][r] * inv1);
    }
  }

  // ---- phase 2: C[32][256] = O1s @ Wo^T, K=256 in 4 blocks of 64 ----
  // wave w owns output cols [w*64, w*64+64): 2 m-tiles x 4 n-tiles.
  floatx4 acc[2][4];
#pragma unroll
  for (int mt = 0; mt < 2; ++mt)
#pragma unroll
    for (int nt = 0; nt < 4; ++nt) acc[mt][nt] = (floatx4)(0.f);

  for (int kb = 0; kb < 4; ++kb) {
    __syncthreads();  // kb=0: O1s visible; kb>0: prior Ws reads done
#pragma unroll
    for (int j = 0; j < 8; ++j) {
      int r0 = (wave * 8 + j) * 8;
      int row = r0 + rsub;
      int c = csub ^ (row & 7);
      const short* gp = Wo + (long)row * 256 + kb * 64 + c * 8;
      short* lp = &u.g.Ws[r0 * 64 + lane * 8];
      __builtin_amdgcn_global_load_lds((const GLOBAL_AS void*)gp,
                                       (LDS_AS void*)lp, 16, 0, 0);
    }
    __syncthreads();
#pragma unroll
    for (int ks = 0; ks < 2; ++ks) {
      int pc = (ks * 4 + quad) ^ x7;
      short8 af[2], bfr[4];
#pragma unroll
      for (int mt = 0; mt < 2; ++mt)
        af[mt] = *(const short8*)&u.g.O1s[(mt * 16 + l15) * 256 + kb * 64 + pc * 8];
#pragma unroll
      for (int nt = 0; nt < 4; ++nt)
        bfr[nt] = *(const short8*)&u.g.Ws[(wave * 64 + nt * 16 + l15) * 64 + pc * 8];
#pragma unroll
      for (int mt = 0; mt < 2; ++mt)
#pragma unroll
        for (int nt = 0; nt < 4; ++nt)
          acc[mt][nt] = __builtin_amdgcn_mfma_f32_16x16x32_bf16(
              af[mt], bfr[nt], acc[mt][nt], 0, 0, 0);
    }
  }

  // ---- epilogue: +bias, m1->m2 perm, X2 = C+pos, V2in = C ----
  int nn = b1 >> 8, ii = (b1 >> 4) & 15, jj = b1 & 15;
  float bv[4];
#pragma unroll
  for (int nt = 0; nt < 4; ++nt) bv[nt] = bias[wave * 64 + nt * 16 + l15];
#pragma unroll
  for (int mt = 0; mt < 2; ++mt) {
#pragma unroll
    for (int r = 0; r < 4; ++r) {
      int qrow = mt * 16 + quad * 4 + r;
      int t = qrow >> 4, bh = (qrow >> 2) & 3, bw = qrow & 3;
      int m2 = (t * 256 + ii * 16 + jj) * 32 + nn * 16 + bh * 4 + bw;
      long xbase = (long)m2 * 256;
      long pbase = ((long)qrow * 512 + b1) * 256;
#pragma unroll
      for (int nt = 0; nt < 4; ++nt) {
        int col = wave * 64 + nt * 16 + l15;
        float val = acc[mt][nt][r] + bv[nt];
        X2[xbase + col] = f2bf(val + bf2f(Xp[pbase + col]));
        V2in[xbase + col] = f2bf(val);
      }
    }
  }
}

// ---------------- stage-2 attention: MFMA flash, no-max softmax -------------
// R6 staging (LDS K + pi-V^T, 2 barriers/chunk) + exp2 no-max softmax.
// grid 2048: bid = qblk*256 + rest, rest = (hh&1)*128 + b2*4 + (hh>>1).
__global__ __launch_bounds__(256) void attn2_mfma(
    const short* __restrict__ Q2, const short* __restrict__ K2,
    const short* __restrict__ V2, short* __restrict__ O2) {
  __shared__ short Ks[64][40];      // [key][d]
  __shared__ short Vt[32][72];      // [d][pi(key)]
  __shared__ short Pw[4][16][72];   // per-wave P [q][pi(key)]
  int bid = blockIdx.x;
  int rest = bid & 255;
  int qblk = bid >> 8;
  int hh = 2 * (rest & 3) + (rest >> 7);
  int b2 = (rest >> 2) & 31;
  int tid = threadIdx.x;
  int wave = tid >> 6, lane = tid & 63;
  int l15 = lane & 15, quad = lane >> 4;

  short8 qf;
  {
    long tok = (long)(qblk * 64 + wave * 16 + l15) * 32 + b2;
    qf = *(const short8*)(Q2 + tok * 256 + hh * 32 + quad * 8);
  }
  floatx4 Oa = (floatx4)(0.f), Ob = (floatx4)(0.f);
  float li[4] = {0.f, 0.f, 0.f, 0.f};

  int skey = tid >> 2;          // K staging: 0..63
  int sd0 = (tid & 3) * 8;
  int vkey = lane;              // V staging
  int vd0 = wave * 8;
  int vcol = (vkey & 15) * 4 + (vkey >> 4);  // pi(key)

  for (int kb = 0; kb < 8; ++kb) {
    if (kb) __syncthreads();
    {  // stage K [64][32] bf16 passthrough
      long tok = (long)(kb * 64 + skey) * 32 + b2;
      *(short8*)&Ks[skey][sd0] = *(const short8*)(K2 + tok * 256 + hh * 32 + sd0);
    }
    {  // stage V^T [32][pi(64)] bf16 passthrough
      long tok = (long)(kb * 64 + vkey) * 32 + b2;
      short8 v = *(const short8*)(V2 + tok * 256 + hh * 32 + vd0);
#pragma unroll
      for (int j = 0; j < 8; ++j) Vt[vd0 + j][vcol] = v[j];
    }
    __syncthreads();
    floatx4 st[4];
#pragma unroll
    for (int kt = 0; kt < 4; ++kt) {
      short8 kf = *(const short8*)&Ks[kt * 16 + l15][quad * 8];
      st[kt] = __builtin_amdgcn_mfma_f32_16x16x32_bf16(qf, kf, (floatx4)(0.f), 0, 0, 0);
    }
#pragma unroll
    for (int r = 0; r < 4; ++r) {
      float p0 = __builtin_amdgcn_exp2f(st[0][r] * EXP2_SCALE);
      float p1 = __builtin_amdgcn_exp2f(st[1][r] * EXP2_SCALE);
      float p2 = __builtin_amdgcn_exp2f(st[2][r] * EXP2_SCALE);
      float p3 = __builtin_amdgcn_exp2f(st[3][r] * EXP2_SCALE);
      li[r] += (p0 + p1) + (p2 + p3);
      short4v pp;
      pp.x = f2bf(p0); pp.y = f2bf(p1); pp.z = f2bf(p2); pp.w = f2bf(p3);
      *(short4v*)&Pw[wave][quad * 4 + r][l15 * 4] = pp;
    }
#pragma unroll
    for (int kk = 0; kk < 2; ++kk) {
      short8 pf = *(const short8*)&Pw[wave][l15][kk * 32 + quad * 8];
      short8 v0 = *(const short8*)&Vt[l15][kk * 32 + quad * 8];
      short8 v1 = *(const short8*)&Vt[16 + l15][kk * 32 + quad * 8];
      Oa = __builtin_amdgcn_mfma_f32_16x16x32_bf16(pf, v0, Oa, 0, 0, 0);
      Ob = __builtin_amdgcn_mfma_f32_16x16x32_bf16(pf, v1, Ob, 0, 0, 0);
    }
  }
#pragma unroll
  for (int r = 0; r < 4; ++r) {
    float s = li[r];
    s += __shfl_xor(s, 1, 64);
    s += __shfl_xor(s, 2, 64);
    s += __shfl_xor(s, 4, 64);
    s += __shfl_xor(s, 8, 64);
    float inv = 1.f / s;
    long tok = (long)(qblk * 64 + wave * 16 + quad * 4 + r) * 32 + b2;
    long a = tok * 256 + hh * 32 + l15;
    O2[a] = f2bf(Oa[r] * inv);
    O2[a + 16] = f2bf(Ob[r] * inv);
  }
}

// ---------------- unpack: [16384,256] fp32 (m2-order) -> out [n,c,t,h,w] ----
__global__ __launch_bounds__(256) void unpack_kernel(
    const float* __restrict__ Y, float* __restrict__ out) {
  __shared__ float tl[64][65];
  int b = blockIdx.x;
  int cb = b & 3;
  int h = (b >> 2) & 63;
  int nt = b >> 8;
  int n = nt >> 1, t = nt & 1;
  int c0 = cb * 64;
  int bh = h >> 4, ii = h & 15;
  int tx = threadIdx.x & 63;
  int ty = threadIdx.x >> 6;
  for (int ww = ty; ww < 64; ww += 4) {
    int bw = ww >> 4, j = ww & 15;
    int l2 = t * 256 + ii * 16 + j;
    int b2 = n * 16 + bh * 4 + bw;
    int m2 = l2 * 32 + b2;
    tl[tx][ww] = Y[(long)m2 * 256 + c0 + tx];
  }
  __syncthreads();
  long ob = (long)n * 2097152 + (long)t * 4096 + (long)h * 64 + tx;
  for (int cc = ty; cc < 64; cc += 4) {
    out[ob + (long)(c0 + cc) * 8192] = tl[cc][tx];
  }
}

extern "C" void kernel_launch(void* const* d_in, const int* in_sizes, int n_in,
                              void* d_out, int out_size, void* d_ws, size_t ws_size,
                              hipStream_t stream) {
  const float* q      = (const float*)d_in[0];
  const float* k      = (const float*)d_in[1];
  const float* v      = (const float*)d_in[2];
  const float* pos    = (const float*)d_in[3];
  const float* wl_in  = (const float*)d_in[4];
  const float* bl_in  = (const float*)d_in[5];
  const float* wl_out = (const float*)d_in[6];
  const float* bl_out = (const float*)d_in[7];
  const float* ws_in  = (const float*)d_in[8];
  const float* bs_in  = (const float*)d_in[9];
  const float* ws_out = (const float*)d_in[10];
  const float* bs_out = (const float*)d_in[11];
  float* out = (float*)d_out;
  char* wsb = (char*)d_ws;
  const size_t SLB = 16777216;  // 16 MB per slot (bf16 tensors use half)
  short* s0 = (short*)(wsb);            // Xp (8 MB)
  short* wbf = (short*)(wsb + SLB / 2); // bf16 weights (1 MB)
  short* s1 = (short*)(wsb + SLB);      // Xq -> Q1? no: Xq -> (free) -> V2
  short* s2 = (short*)(wsb + 2 * SLB);  // Xk -> V2in -> Yfinal(fp32)
  short* s3 = (short*)(wsb + 3 * SLB);  // Xv -> X2 -> O2
  short* s4 = (short*)(wsb + 4 * SLB);  // Q1
  short* s5 = (short*)(wsb + 5 * SLB);  // K1 -> Q2
  short* s6 = (short*)(wsb + 6 * SLB);  // V1 -> K2

  pack_kernel<<<1024, 256, 0, stream>>>(q, k, v, pos, s0, s1, s2, s3,
                                        wl_in, wl_out, ws_in, ws_out, wbf);

  dim3 g3(128, 4, 3);
  dim3 g1(128, 4, 1);
  // stage-1 Q/K/V: z0 Xq->Q1, z1 Xk->K1, z2 Xv->V1
  gemm_tri<false><<<g3, 256, 0, stream>>>(s1, s2, s3, wbf, bl_in, s4, s5, s6);

  // fused attn1 + out-proj + perm + pos: X2 -> s3, V2in -> s2
  attn1_fused<<<512, 256, 0, stream>>>(s4, s5, s6, s0, wbf + 196608, bl_out,
                                       s3, s2);

  // stage-2 Q/K/V: z0 X2->Q2, z1 X2->K2, z2 V2in->V2
  gemm_tri<false><<<g3, 256, 0, stream>>>(s3, s3, s2, wbf + 262144, bs_in,
                                          s5, s6, s1);

  attn2_mfma<<<2048, 256, 0, stream>>>(s5, s6, s1, s3);   // O2 -> s3
  // Yfinal (fp32) = O2 @ ws_out^T
  gemm_tri<true><<<g1, 256, 0, stream>>>(s3, s3, s3, wbf + 458752, bs_out,
                                         s2, s2, s2);

  unpack_kernel<<<1024, 256, 0, stream>>>((const float*)s2, out);
}

// Round 2
// 203.146 us; speedup vs baseline: 1.0899x; 1.0314x over previous
//
#include <hip/hip_runtime.h>
#include <math.h>

// Problem constants: n=2, c=256, t=2, h=64, w=64; HB=WB=16, bn_h=bn_w=4;
// NHEAD=8, d=32. Stage1: L1=32 tokens x B1=512 batch. Stage2: L2=512 x B2=32.
// Token id m1 = l1*512 + b1, l1=(t*4+bh)*4+bw, b1=n*256+i*16+j.
// Token id m2 = l2*32 + b2,  l2=t*256+i*16+j,  b2=n*16+bh*4+bw.
// R12 = R11 with the stage-2 in-projection also fused into attn1 (attn1_mega):
// after the out-proj GEMM, X2s (=C+bias+pos) and Vins (=C+bias) are spilled
// to LDS (16 KB each, X2s overlaying the dead O1s region) and three more
// 32x256x256 GEMMs against ws_{q,k,v} produce Q2/K2/V2 directly at permuted
// m2 rows. Removes the stage-2 gemm_tri kernel (~40 MB HBM round trip + 1
// launch). LDS union is exactly 64 KB -> 2 blocks/CU, matching grid 512.

#define SCALE_D32 0.17677669529663687f       // 1/sqrt(32)
#define EXP2_SCALE 0.25508680987930193f      // SCALE_D32 * log2(e)
#define GLOBAL_AS __attribute__((address_space(1)))
#define LDS_AS __attribute__((address_space(3)))

typedef short short8 __attribute__((ext_vector_type(8)));   // 8 bf16 = 16B
typedef short short4v __attribute__((ext_vector_type(4)));  // 4 bf16 = 8B
typedef short short2v __attribute__((ext_vector_type(2)));  // 2 bf16 = 4B
typedef float floatx4 __attribute__((ext_vector_type(4)));  // MFMA C/D frag

__device__ __forceinline__ short f2bf(float f) {
  union { float f; unsigned u; } x;
  x.f = f;
  unsigned r = x.u + 0x7fffu + ((x.u >> 16) & 1u);  // RNE
  return (short)(r >> 16);
}
__device__ __forceinline__ float bf2f(short s) {
  union { unsigned u; float f; } x;
  x.u = ((unsigned)(unsigned short)s) << 16;
  return x.f;
}

// physical index into a swizzled [32][256] bf16 A-tile (matches gemm_tri's
// As layout per 64-k-block: chunk' = chunk ^ (row&7), 8-short granularity)
__device__ __forceinline__ int o1s_phys(int q, int ch) {
  return q * 256 + (ch & ~63) + ((((ch >> 3) & 7) ^ (q & 7)) << 3) + (ch & 7);
}

// stage one 256x64 bf16 W k-block into LDS, gemm_tri swizzle, 16B DMA
__device__ __forceinline__ void stage_w(short* Wsl, const short* Wg, int kb,
                                        int wave, int lane, int rsub, int csub) {
#pragma unroll
  for (int j = 0; j < 8; ++j) {
    int r0 = (wave * 8 + j) * 8;
    int row = r0 + rsub;
    int c = csub ^ (row & 7);
    const short* gp = Wg + (long)row * 256 + kb * 64 + c * 8;
    short* lp = &Wsl[r0 * 64 + lane * 8];
    __builtin_amdgcn_global_load_lds((const GLOBAL_AS void*)gp,
                                     (LDS_AS void*)lp, 16, 0, 0);
  }
}

// ---- pack: [n,c,t,h,w] fp32 -> token-major [16384,256] bf16; + weight cvt --
__global__ __launch_bounds__(256) void pack_kernel(
    const float* __restrict__ q, const float* __restrict__ k,
    const float* __restrict__ v, const float* __restrict__ pos,
    short* __restrict__ Xp, short* __restrict__ Xq,
    short* __restrict__ Xk, short* __restrict__ Xv,
    const float* __restrict__ wl_in, const float* __restrict__ wl_out,
    const float* __restrict__ ws_in, const float* __restrict__ ws_out,
    short* __restrict__ wbf) {
  __shared__ float tP[64][65];
  __shared__ float tX[64][65];
  int b = blockIdx.x;
  int cb = b & 3;
  int h  = (b >> 2) & 63;
  int nt = b >> 8;
  int n = nt >> 1, t = nt & 1;
  int c0 = cb * 64;
  int bh = h >> 4, ii = h & 15;
  long inbase = (long)n * 2097152 + (long)t * 4096 + (long)h * 64;
  int tx = threadIdx.x & 63;
  int ty = threadIdx.x >> 6;  // 0..3

  for (int cc = ty; cc < 64; cc += 4) {
    long a = inbase + (long)(c0 + cc) * 8192 + tx;
    tP[cc][tx] = pos[a];
    tX[cc][tx] = q[a];
  }
  __syncthreads();
  for (int ww = ty; ww < 64; ww += 4) {
    int bw = ww >> 4, j = ww & 15;
    int m1 = (((t * 4 + bh) * 4 + bw) * 512) + n * 256 + ii * 16 + j;
    long o = (long)m1 * 256 + c0 + tx;
    float pv = tP[tx][ww];
    Xp[o] = f2bf(pv);
    Xq[o] = f2bf(tX[tx][ww] + pv);
  }
  __syncthreads();
  for (int cc = ty; cc < 64; cc += 4) {
    long a = inbase + (long)(c0 + cc) * 8192 + tx;
    tX[cc][tx] = k[a];
  }
  __syncthreads();
  for (int ww = ty; ww < 64; ww += 4) {
    int bw = ww >> 4, j = ww & 15;
    int m1 = (((t * 4 + bh) * 4 + bw) * 512) + n * 256 + ii * 16 + j;
    long o = (long)m1 * 256 + c0 + tx;
    Xk[o] = f2bf(tX[tx][ww] + tP[tx][ww]);
  }
  __syncthreads();
  for (int cc = ty; cc < 64; cc += 4) {
    long a = inbase + (long)(c0 + cc) * 8192 + tx;
    tX[cc][tx] = v[a];
  }
  __syncthreads();
  for (int ww = ty; ww < 64; ww += 4) {
    int bw = ww >> 4, j = ww & 15;
    int m1 = (((t * 4 + bh) * 4 + bw) * 512) + n * 256 + ii * 16 + j;
    long o = (long)m1 * 256 + c0 + tx;
    Xv[o] = f2bf(tX[tx][ww]);
  }
  // weight convert tail: 1024 blocks x 256 threads x 2 floats = 524288
  int idx = (blockIdx.x * 256 + threadIdx.x) * 2;
  const float* wp;
  if (idx < 196608) wp = wl_in + idx;
  else if (idx < 262144) wp = wl_out + (idx - 196608);
  else if (idx < 458752) wp = ws_in + (idx - 262144);
  else wp = ws_out + (idx - 458752);
  float2 wv = *(const float2*)wp;
  wbf[idx] = f2bf(wv.x);
  wbf[idx + 1] = f2bf(wv.y);
}

// ------- m97-style bf16 TN GEMM triple: C_z = A_z @ W_z^T + b_z -------------
// Tile 128x64, BK=64, global_load_lds 16B staging, XOR swizzle pc=c^(row&7).
template <bool OUT32>
__global__ __launch_bounds__(256) void gemm_tri(
    const short* __restrict__ A0, const short* __restrict__ A1,
    const short* __restrict__ A2, const short* __restrict__ W0,
    const float* __restrict__ bias0, void* __restrict__ C0,
    void* __restrict__ C1, void* __restrict__ C2) {
  __shared__ short As[128 * 64];  // 16 KB
  __shared__ short Ws[64 * 64];   //  8 KB
  int z = blockIdx.z;
  const short* A = (z == 0) ? A0 : ((z == 1) ? A1 : A2);
  const short* Wb = W0 + z * 65536;
  const float* bias = bias0 + z * 256;
  void* Csel = (z == 0) ? C0 : ((z == 1) ? C1 : C2);
  int m0 = blockIdx.x * 128;
  int n0 = blockIdx.y * 64;
  int tid = threadIdx.x;
  int lane = tid & 63, wave = tid >> 6;
  int wm = wave >> 1, wn = wave & 1;
  int l15 = lane & 15, quad = lane >> 4;
  int x7 = l15 & 7;
  int rsub = lane >> 3;   // 0..7: row within 8-row staging chunk
  int csub = lane & 7;    // logical col16 before swizzle

  floatx4 acc[4][2];
#pragma unroll
  for (int mt = 0; mt < 4; ++mt)
#pragma unroll
    for (int nt = 0; nt < 2; ++nt) acc[mt][nt] = (floatx4)(0.f);

  for (int kb = 0; kb < 4; ++kb) {
    int k0 = kb * 64;
    if (kb) __syncthreads();
#pragma unroll
    for (int j = 0; j < 4; ++j) {
      int r0 = (wave * 4 + j) * 8;
      int row = r0 + rsub;
      int c = csub ^ (row & 7);
      const short* gp = A + (long)(m0 + row) * 256 + k0 + c * 8;
      short* lp = &As[r0 * 64 + lane * 8];
      __builtin_amdgcn_global_load_lds((const GLOBAL_AS void*)gp,
                                       (LDS_AS void*)lp, 16, 0, 0);
    }
#pragma unroll
    for (int j = 0; j < 2; ++j) {
      int r0 = (wave * 2 + j) * 8;
      int row = r0 + rsub;
      int c = csub ^ (row & 7);
      const short* gp = Wb + (long)(n0 + row) * 256 + k0 + c * 8;
      short* lp = &Ws[r0 * 64 + lane * 8];
      __builtin_amdgcn_global_load_lds((const GLOBAL_AS void*)gp,
                                       (LDS_AS void*)lp, 16, 0, 0);
    }
    __syncthreads();
#pragma unroll
    for (int ks = 0; ks < 2; ++ks) {
      int pc = (ks * 4 + quad) ^ x7;
      short8 af[4], bfr[2];
#pragma unroll
      for (int mt = 0; mt < 4; ++mt) {
        int row = wm * 64 + mt * 16 + l15;
        af[mt] = *(const short8*)&As[row * 64 + pc * 8];
      }
#pragma unroll
      for (int nt = 0; nt < 2; ++nt) {
        int row = wn * 32 + nt * 16 + l15;
        bfr[nt] = *(const short8*)&Ws[row * 64 + pc * 8];
      }
#pragma unroll
      for (int mt = 0; mt < 4; ++mt)
#pragma unroll
        for (int nt = 0; nt < 2; ++nt)
          acc[mt][nt] = __builtin_amdgcn_mfma_f32_16x16x32_bf16(
              af[mt], bfr[nt], acc[mt][nt], 0, 0, 0);
    }
  }
  float bia0 = bias[n0 + wn * 32 + l15];
  float bia1 = bias[n0 + wn * 32 + 16 + l15];
#pragma unroll
  for (int mt = 0; mt < 4; ++mt) {
#pragma unroll
    for (int r = 0; r < 4; ++r) {
      int row = m0 + wm * 64 + mt * 16 + quad * 4 + r;
      long base = (long)row * 256 + n0 + wn * 32 + l15;
      if (OUT32) {
        float* C = (float*)Csel;
        C[base] = acc[mt][0][r] + bia0;
        C[base + 16] = acc[mt][1][r] + bia1;
      } else {
        short* C = (short*)Csel;
        C[base] = f2bf(acc[mt][0][r] + bia0);
        C[base + 16] = f2bf(acc[mt][1][r] + bia1);
      }
    }
  }
}

// ---- stage-1 attention + out-proj + perm + pos + stage-2 in-proj, fused ----
// One block (4 waves) per b1. Phase 1 = R10 attn1 (verified). Phase 2a:
// C1 = O1s @ wl_out^T (O1s spilled swizzled to LDS). Spill X2s = C1+b+pos
// (into dead O1s region) and Vins = C1+b. Phase 2b: three GEMMs vs ws_{q,k,v}
// (Ws staged per 64-k-block, identical machinery), epilogue writes Q2/K2/V2
// at permuted m2 rows with stage-2 in-proj bias.
__global__ __launch_bounds__(256) void attn1_mega(
    const short* __restrict__ Q1, const short* __restrict__ K1,
    const short* __restrict__ V1, const short* __restrict__ Xp,
    const short* __restrict__ Wo, const float* __restrict__ bias_o,
    const short* __restrict__ Wsin, const float* __restrict__ bias_sin,
    short* __restrict__ Q2, short* __restrict__ K2, short* __restrict__ V2) {
  __shared__ union {
    struct {                      // phase 1 (attention): 37376 B
      short Vs[32][264];          // [key][c] (all heads), +8 pad (528B rows)
      short Vt[4][32][40];        // per-wave [d][pi2(key)], 80B rows
      short Pw[4][32][40];        // per-wave [q][pi2(key)], 80B rows
    } a;
    struct {                      // phase 2 (GEMMs): 65536 B exactly
      short O1s[32 * 256];        // swizzled O tile; later X2s (=C1+b+pos)
      short Vins[32 * 256];       // swizzled Vin tile (=C1+b)
      short Ws[256 * 64];         // W k-block, swizzled
    } g;
  } u;
  int b1 = blockIdx.x;
  int tid = threadIdx.x;
  int wave = tid >> 6, lane = tid & 63;
  int l15 = lane & 15, quad = lane >> 4;
  int x7 = l15 & 7;
  int rsub = lane >> 3;
  int csub = lane & 7;

  // ---- phase 1: stage V (full 32x256 tile, 4 passes) ----
#pragma unroll
  for (int p = 0; p < 4; ++p) {
    int idx = p * 256 + tid;       // 0..1023
    int row = idx >> 5;            // 0..31
    int c8 = idx & 31;             // 0..31 (short8 chunk within row)
    *(short8*)&u.a.Vs[row][c8 * 8] =
        *(const short8*)(V1 + ((long)row * 512 + b1) * 256 + c8 * 8);
  }
  __syncthreads();

  int key = lane & 31;
  int dh = (lane >> 5) * 16;                 // 0 or 16
  int pc2 = 2 * (key & 15) + (key >> 4);     // pi2(key)

  floatx4 oacc[2][4];    // [h2][o00,o01,o10,o11]
  float lsum[2][2][4];   // [h2][li0/li1][r]

#pragma unroll
  for (int h2 = 0; h2 < 2; ++h2) {
    int hh = wave * 2 + h2;
    // Q/K fragments direct from global: m=l15(+16), k=d=quad*8+j
    long fbase = ((long)l15 * 512 + b1) * 256 + hh * 32 + quad * 8;
    short8 qf0 = *(const short8*)(Q1 + fbase);
    short8 qf1 = *(const short8*)(Q1 + fbase + 16 * 512 * 256);
    short8 kf0 = *(const short8*)(K1 + fbase);
    short8 kf1 = *(const short8*)(K1 + fbase + 16 * 512 * 256);
    // V^T for this head: Vt[d][pi2(key)]; lanes 0-31: d 0..15, 32-63: 16..31
    short8 v0 = *(const short8*)&u.a.Vs[key][hh * 32 + dh];
    short8 v1 = *(const short8*)&u.a.Vs[key][hh * 32 + dh + 8];
#pragma unroll
    for (int j = 0; j < 8; ++j) {
      u.a.Vt[wave][dh + j][pc2] = v0[j];
      u.a.Vt[wave][dh + 8 + j][pc2] = v1[j];
    }
    // S = Q K^T (4 tiles)
    floatx4 s00 = __builtin_amdgcn_mfma_f32_16x16x32_bf16(qf0, kf0, (floatx4)(0.f), 0, 0, 0);
    floatx4 s01 = __builtin_amdgcn_mfma_f32_16x16x32_bf16(qf0, kf1, (floatx4)(0.f), 0, 0, 0);
    floatx4 s10 = __builtin_amdgcn_mfma_f32_16x16x32_bf16(qf1, kf0, (floatx4)(0.f), 0, 0, 0);
    floatx4 s11 = __builtin_amdgcn_mfma_f32_16x16x32_bf16(qf1, kf1, (floatx4)(0.f), 0, 0, 0);
    // no-max softmax; P[q][pi2(k)]: key tiles j=0,1 -> cols 2*l15, 2*l15+1
    float li0[4], li1[4];
#pragma unroll
    for (int r = 0; r < 4; ++r) {
      float p00 = __builtin_amdgcn_exp2f(s00[r] * EXP2_SCALE);
      float p01 = __builtin_amdgcn_exp2f(s01[r] * EXP2_SCALE);
      float p10 = __builtin_amdgcn_exp2f(s10[r] * EXP2_SCALE);
      float p11 = __builtin_amdgcn_exp2f(s11[r] * EXP2_SCALE);
      li0[r] = p00 + p01;
      li1[r] = p10 + p11;
      short2v pa, pb;
      pa.x = f2bf(p00); pa.y = f2bf(p01);
      pb.x = f2bf(p10); pb.y = f2bf(p11);
      *(short2v*)&u.a.Pw[wave][quad * 4 + r][2 * l15] = pa;
      *(short2v*)&u.a.Pw[wave][16 + quad * 4 + r][2 * l15] = pb;
    }
#pragma unroll
    for (int r = 0; r < 4; ++r) {
      li0[r] += __shfl_xor(li0[r], 1, 64);
      li0[r] += __shfl_xor(li0[r], 2, 64);
      li0[r] += __shfl_xor(li0[r], 4, 64);
      li0[r] += __shfl_xor(li0[r], 8, 64);
      li1[r] += __shfl_xor(li1[r], 1, 64);
      li1[r] += __shfl_xor(li1[r], 2, 64);
      li1[r] += __shfl_xor(li1[r], 4, 64);
      li1[r] += __shfl_xor(li1[r], 8, 64);
      lsum[h2][0][r] = li0[r];
      lsum[h2][1][r] = li1[r];
    }
    // PV: O[32q][32d] = P[32q][32k] V[32k][32d] (k pi2-ordered both sides)
    short8 pf0 = *(const short8*)&u.a.Pw[wave][l15][quad * 8];
    short8 pf1 = *(const short8*)&u.a.Pw[wave][16 + l15][quad * 8];
    short8 vt0 = *(const short8*)&u.a.Vt[wave][l15][quad * 8];
    short8 vt1 = *(const short8*)&u.a.Vt[wave][16 + l15][quad * 8];
    oacc[h2][0] = __builtin_amdgcn_mfma_f32_16x16x32_bf16(pf0, vt0, (floatx4)(0.f), 0, 0, 0);
    oacc[h2][1] = __builtin_amdgcn_mfma_f32_16x16x32_bf16(pf0, vt1, (floatx4)(0.f), 0, 0, 0);
    oacc[h2][2] = __builtin_amdgcn_mfma_f32_16x16x32_bf16(pf1, vt0, (floatx4)(0.f), 0, 0, 0);
    oacc[h2][3] = __builtin_amdgcn_mfma_f32_16x16x32_bf16(pf1, vt1, (floatx4)(0.f), 0, 0, 0);
  }

  // all attn LDS reads done before O1s overlays Vs
  __syncthreads();

  // ---- spill normalized O tile to swizzled LDS (bf16, same as old O1) ----
#pragma unroll
  for (int h2 = 0; h2 < 2; ++h2) {
    int hh = wave * 2 + h2;
    int cA = hh * 32 + l15;
    int cB = cA + 16;
#pragma unroll
    for (int r = 0; r < 4; ++r) {
      float inv0 = 1.f / lsum[h2][0][r];
      float inv1 = 1.f / lsum[h2][1][r];
      int qa = quad * 4 + r, qb = 16 + quad * 4 + r;
      u.g.O1s[o1s_phys(qa, cA)] = f2bf(oacc[h2][0][r] * inv0);
      u.g.O1s[o1s_phys(qa, cB)] = f2bf(oacc[h2][1][r] * inv0);
      u.g.O1s[o1s_phys(qb, cA)] = f2bf(oacc[h2][2][r] * inv1);
      u.g.O1s[o1s_phys(qb, cB)] = f2bf(oacc[h2][3][r] * inv1);
    }
  }

  // ---- phase 2a: C1[32][256] = O1s @ Wo^T, K=256 in 4 blocks of 64 ----
  // wave w owns output cols [w*64, w*64+64): 2 m-tiles x 4 n-tiles.
  floatx4 acc1[2][4];
#pragma unroll
  for (int mt = 0; mt < 2; ++mt)
#pragma unroll
    for (int nt = 0; nt < 4; ++nt) acc1[mt][nt] = (floatx4)(0.f);

  for (int kb = 0; kb < 4; ++kb) {
    __syncthreads();  // kb=0: O1s spill visible; kb>0: prior Ws reads done
    stage_w(u.g.Ws, Wo, kb, wave, lane, rsub, csub);
    __syncthreads();
#pragma unroll
    for (int ks = 0; ks < 2; ++ks) {
      int pc = (ks * 4 + quad) ^ x7;
      short8 af[2], bfr[4];
#pragma unroll
      for (int mt = 0; mt < 2; ++mt)
        af[mt] = *(const short8*)&u.g.O1s[(mt * 16 + l15) * 256 + kb * 64 + pc * 8];
#pragma unroll
      for (int nt = 0; nt < 4; ++nt)
        bfr[nt] = *(const short8*)&u.g.Ws[(wave * 64 + nt * 16 + l15) * 64 + pc * 8];
#pragma unroll
      for (int mt = 0; mt < 2; ++mt)
#pragma unroll
        for (int nt = 0; nt < 4; ++nt)
          acc1[mt][nt] = __builtin_amdgcn_mfma_f32_16x16x32_bf16(
              af[mt], bfr[nt], acc1[mt][nt], 0, 0, 0);
    }
  }

  // O1s fully consumed; overwrite with X2s, fill Vins
  __syncthreads();
  {
    float bvo[4];
#pragma unroll
    for (int nt = 0; nt < 4; ++nt) bvo[nt] = bias_o[wave * 64 + nt * 16 + l15];
#pragma unroll
    for (int mt = 0; mt < 2; ++mt) {
#pragma unroll
      for (int r = 0; r < 4; ++r) {
        int qrow = mt * 16 + quad * 4 + r;
        long pbase = ((long)qrow * 512 + b1) * 256;
#pragma unroll
        for (int nt = 0; nt < 4; ++nt) {
          int col = wave * 64 + nt * 16 + l15;
          float val = acc1[mt][nt][r] + bvo[nt];
          int ph = o1s_phys(qrow, col);
          u.g.Vins[ph] = f2bf(val);
          u.g.O1s[ph] = f2bf(val + bf2f(Xp[pbase + col]));  // X2s
        }
      }
    }
  }

  // ---- phase 2b: Q2/K2/V2 = {X2s,X2s,Vins} @ ws_{q,k,v}^T + b ----
  int nn = b1 >> 8, ii = (b1 >> 4) & 15, jj = b1 & 15;
#pragma unroll
  for (int z = 0; z < 3; ++z) {
    const short* Wz = Wsin + z * 65536;
    const short* Ab = (z < 2) ? (const short*)u.g.O1s : (const short*)u.g.Vins;
    short* outz = (z == 0) ? Q2 : ((z == 1) ? K2 : V2);
    float bz[4];
#pragma unroll
    for (int nt = 0; nt < 4; ++nt)
      bz[nt] = bias_sin[z * 256 + wave * 64 + nt * 16 + l15];

    floatx4 acc[2][4];
#pragma unroll
    for (int mt = 0; mt < 2; ++mt)
#pragma unroll
      for (int nt = 0; nt < 4; ++nt) acc[mt][nt] = (floatx4)(0.f);

    for (int kb = 0; kb < 4; ++kb) {
      __syncthreads();  // spill/X2s visible (z=0,kb=0); prior Ws reads done
      stage_w(u.g.Ws, Wz, kb, wave, lane, rsub, csub);
      __syncthreads();
#pragma unroll
      for (int ks = 0; ks < 2; ++ks) {
        int pc = (ks * 4 + quad) ^ x7;
        short8 af[2], bfr[4];
#pragma unroll
        for (int mt = 0; mt < 2; ++mt)
          af[mt] = *(const short8*)&Ab[(mt * 16 + l15) * 256 + kb * 64 + pc * 8];
#pragma unroll
        for (int nt = 0; nt < 4; ++nt)
          bfr[nt] = *(const short8*)&u.g.Ws[(wave * 64 + nt * 16 + l15) * 64 + pc * 8];
#pragma unroll
        for (int mt = 0; mt < 2; ++mt)
#pragma unroll
          for (int nt = 0; nt < 4; ++nt)
            acc[mt][nt] = __builtin_amdgcn_mfma_f32_16x16x32_bf16(
                af[mt], bfr[nt], acc[mt][nt], 0, 0, 0);
      }
    }

    // epilogue: +bias, m1->m2 perm, store
#pragma unroll
    for (int mt = 0; mt < 2; ++mt) {
#pragma unroll
      for (int r = 0; r < 4; ++r) {
        int qrow = mt * 16 + quad * 4 + r;
        int t = qrow >> 4, bh = (qrow >> 2) & 3, bw = qrow & 3;
        int m2 = (t * 256 + ii * 16 + jj) * 32 + nn * 16 + bh * 4 + bw;
        long xbase = (long)m2 * 256;
#pragma unroll
        for (int nt = 0; nt < 4; ++nt) {
          int col = wave * 64 + nt * 16 + l15;
          outz[xbase + col] = f2bf(acc[mt][nt][r] + bz[nt]);
        }
      }
    }
  }
}

// ---------------- stage-2 attention: MFMA flash, no-max softmax -------------
// R6 staging (LDS K + pi-V^T, 2 barriers/chunk) + exp2 no-max softmax.
// grid 2048: bid = qblk*256 + rest, rest = (hh&1)*128 + b2*4 + (hh>>1).
__global__ __launch_bounds__(256) void attn2_mfma(
    const short* __restrict__ Q2, const short* __restrict__ K2,
    const short* __restrict__ V2, short* __restrict__ O2) {
  __shared__ short Ks[64][40];      // [key][d]
  __shared__ short Vt[32][72];      // [d][pi(key)]
  __shared__ short Pw[4][16][72];   // per-wave P [q][pi(key)]
  int bid = blockIdx.x;
  int rest = bid & 255;
  int qblk = bid >> 8;
  int hh = 2 * (rest & 3) + (rest >> 7);
  int b2 = (rest >> 2) & 31;
  int tid = threadIdx.x;
  int wave = tid >> 6, lane = tid & 63;
  int l15 = lane & 15, quad = lane >> 4;

  short8 qf;
  {
    long tok = (long)(qblk * 64 + wave * 16 + l15) * 32 + b2;
    qf = *(const short8*)(Q2 + tok * 256 + hh * 32 + quad * 8);
  }
  floatx4 Oa = (floatx4)(0.f), Ob = (floatx4)(0.f);
  float li[4] = {0.f, 0.f, 0.f, 0.f};

  int skey = tid >> 2;          // K staging: 0..63
  int sd0 = (tid & 3) * 8;
  int vkey = lane;              // V staging
  int vd0 = wave * 8;
  int vcol = (vkey & 15) * 4 + (vkey >> 4);  // pi(key)

  for (int kb = 0; kb < 8; ++kb) {
    if (kb) __syncthreads();
    {  // stage K [64][32] bf16 passthrough
      long tok = (long)(kb * 64 + skey) * 32 + b2;
      *(short8*)&Ks[skey][sd0] = *(const short8*)(K2 + tok * 256 + hh * 32 + sd0);
    }
    {  // stage V^T [32][pi(64)] bf16 passthrough
      long tok = (long)(kb * 64 + vkey) * 32 + b2;
      short8 v = *(const short8*)(V2 + tok * 256 + hh * 32 + vd0);
#pragma unroll
      for (int j = 0; j < 8; ++j) Vt[vd0 + j][vcol] = v[j];
    }
    __syncthreads();
    floatx4 st[4];
#pragma unroll
    for (int kt = 0; kt < 4; ++kt) {
      short8 kf = *(const short8*)&Ks[kt * 16 + l15][quad * 8];
      st[kt] = __builtin_amdgcn_mfma_f32_16x16x32_bf16(qf, kf, (floatx4)(0.f), 0, 0, 0);
    }
#pragma unroll
    for (int r = 0; r < 4; ++r) {
      float p0 = __builtin_amdgcn_exp2f(st[0][r] * EXP2_SCALE);
      float p1 = __builtin_amdgcn_exp2f(st[1][r] * EXP2_SCALE);
      float p2 = __builtin_amdgcn_exp2f(st[2][r] * EXP2_SCALE);
      float p3 = __builtin_amdgcn_exp2f(st[3][r] * EXP2_SCALE);
      li[r] += (p0 + p1) + (p2 + p3);
      short4v pp;
      pp.x = f2bf(p0); pp.y = f2bf(p1); pp.z = f2bf(p2); pp.w = f2bf(p3);
      *(short4v*)&Pw[wave][quad * 4 + r][l15 * 4] = pp;
    }
#pragma unroll
    for (int kk = 0; kk < 2; ++kk) {
      short8 pf = *(const short8*)&Pw[wave][l15][kk * 32 + quad * 8];
      short8 v0 = *(const short8*)&Vt[l15][kk * 32 + quad * 8];
      short8 v1 = *(const short8*)&Vt[16 + l15][kk * 32 + quad * 8];
      Oa = __builtin_amdgcn_mfma_f32_16x16x32_bf16(pf, v0, Oa, 0, 0, 0);
      Ob = __builtin_amdgcn_mfma_f32_16x16x32_bf16(pf, v1, Ob, 0, 0, 0);
    }
  }
#pragma unroll
  for (int r = 0; r < 4; ++r) {
    float s = li[r];
    s += __shfl_xor(s, 1, 64);
    s += __shfl_xor(s, 2, 64);
    s += __shfl_xor(s, 4, 64);
    s += __shfl_xor(s, 8, 64);
    float inv = 1.f / s;
    long tok = (long)(qblk * 64 + wave * 16 + quad * 4 + r) * 32 + b2;
    long a = tok * 256 + hh * 32 + l15;
    O2[a] = f2bf(Oa[r] * inv);
    O2[a + 16] = f2bf(Ob[r] * inv);
  }
}

// ---------------- unpack: [16384,256] fp32 (m2-order) -> out [n,c,t,h,w] ----
__global__ __launch_bounds__(256) void unpack_kernel(
    const float* __restrict__ Y, float* __restrict__ out) {
  __shared__ float tl[64][65];
  int b = blockIdx.x;
  int cb = b & 3;
  int h = (b >> 2) & 63;
  int nt = b >> 8;
  int n = nt >> 1, t = nt & 1;
  int c0 = cb * 64;
  int bh = h >> 4, ii = h & 15;
  int tx = threadIdx.x & 63;
  int ty = threadIdx.x >> 6;
  for (int ww = ty; ww < 64; ww += 4) {
    int bw = ww >> 4, j = ww & 15;
    int l2 = t * 256 + ii * 16 + j;
    int b2 = n * 16 + bh * 4 + bw;
    int m2 = l2 * 32 + b2;
    tl[tx][ww] = Y[(long)m2 * 256 + c0 + tx];
  }
  __syncthreads();
  long ob = (long)n * 2097152 + (long)t * 4096 + (long)h * 64 + tx;
  for (int cc = ty; cc < 64; cc += 4) {
    out[ob + (long)(c0 + cc) * 8192] = tl[cc][tx];
  }
}

extern "C" void kernel_launch(void* const* d_in, const int* in_sizes, int n_in,
                              void* d_out, int out_size, void* d_ws, size_t ws_size,
                              hipStream_t stream) {
  const float* q      = (const float*)d_in[0];
  const float* k      = (const float*)d_in[1];
  const float* v      = (const float*)d_in[2];
  const float* pos    = (const float*)d_in[3];
  const float* wl_in  = (const float*)d_in[4];
  const float* bl_in  = (const float*)d_in[5];
  const float* wl_out = (const float*)d_in[6];
  const float* bl_out = (const float*)d_in[7];
  const float* ws_in  = (const float*)d_in[8];
  const float* bs_in  = (const float*)d_in[9];
  const float* ws_out = (const float*)d_in[10];
  const float* bs_out = (const float*)d_in[11];
  float* out = (float*)d_out;
  char* wsb = (char*)d_ws;
  const size_t SLB = 16777216;  // 16 MB per slot (bf16 tensors use half)
  short* s0 = (short*)(wsb);            // Xp (8 MB)
  short* wbf = (short*)(wsb + SLB / 2); // bf16 weights (1 MB)
  short* s1 = (short*)(wsb + SLB);      // Xq -> Q2
  short* s2 = (short*)(wsb + 2 * SLB);  // Xk -> K2 -> Yfinal(fp32)
  short* s3 = (short*)(wsb + 3 * SLB);  // Xv -> V2
  short* s4 = (short*)(wsb + 4 * SLB);  // Q1 -> O2
  short* s5 = (short*)(wsb + 5 * SLB);  // K1
  short* s6 = (short*)(wsb + 6 * SLB);  // V1

  pack_kernel<<<1024, 256, 0, stream>>>(q, k, v, pos, s0, s1, s2, s3,
                                        wl_in, wl_out, ws_in, ws_out, wbf);

  dim3 g3(128, 4, 3);
  dim3 g1(128, 4, 1);
  // stage-1 Q/K/V: z0 Xq->Q1, z1 Xk->K1, z2 Xv->V1
  gemm_tri<false><<<g3, 256, 0, stream>>>(s1, s2, s3, wbf, bl_in, s4, s5, s6);

  // fused attn1 + out-proj + perm + pos + stage-2 in-proj:
  // Q2 -> s1, K2 -> s2, V2 -> s3
  attn1_mega<<<512, 256, 0, stream>>>(s4, s5, s6, s0, wbf + 196608, bl_out,
                                      wbf + 262144, bs_in, s1, s2, s3);

  attn2_mfma<<<2048, 256, 0, stream>>>(s1, s2, s3, s4);   // O2 -> s4
  // Yfinal (fp32) = O2 @ ws_out^T
  gemm_tri<true><<<g1, 256, 0, stream>>>(s4, s4, s4, wbf + 458752, bs_out,
                                         s2, s2, s2);

  unpack_kernel<<<1024, 256, 0, stream>>>((const float*)s2, out);
}

// Round 3
// 202.828 us; speedup vs baseline: 1.0916x; 1.0016x over previous
//
#include <hip/hip_runtime.h>
#include <math.h>

// Problem constants: n=2, c=256, t=2, h=64, w=64; HB=WB=16, bn_h=bn_w=4;
// NHEAD=8, d=32. Stage1: L1=32 tokens x B1=512 batch. Stage2: L2=512 x B2=32.
// Token id m1 = l1*512 + b1, l1=(t*4+bh)*4+bw, b1=n*256+i*16+j.
// Token id m2 = l2*32 + b2,  l2=t*256+i*16+j,  b2=n*16+bh*4+bw.
// R13 = R12 with the stage-1 in-projection also fused (attn1_giga): per
// block, Xq/Xk/Xv 32x256 tiles are staged to swizzled LDS, three GEMMs vs
// wl_in produce Q1/K1/V1 IN PLACE (same regions), attention reads frags
// from LDS, then out-proj + perm + pos + stage-2 in-proj as in R12.
// Removes the stage-1 gemm_tri kernel (~48 MB HBM round trip + 1 launch).
// LDS: R1/R2/R3 (16 KB each) + R4 32 KB = 80 KB -> 2 blocks/CU, grid 512.

#define SCALE_D32 0.17677669529663687f       // 1/sqrt(32)
#define EXP2_SCALE 0.25508680987930193f      // SCALE_D32 * log2(e)
#define GLOBAL_AS __attribute__((address_space(1)))
#define LDS_AS __attribute__((address_space(3)))

typedef short short8 __attribute__((ext_vector_type(8)));   // 8 bf16 = 16B
typedef short short4v __attribute__((ext_vector_type(4)));  // 4 bf16 = 8B
typedef short short2v __attribute__((ext_vector_type(2)));  // 2 bf16 = 4B
typedef float floatx4 __attribute__((ext_vector_type(4)));  // MFMA C/D frag

__device__ __forceinline__ short f2bf(float f) {
  union { float f; unsigned u; } x;
  x.f = f;
  unsigned r = x.u + 0x7fffu + ((x.u >> 16) & 1u);  // RNE
  return (short)(r >> 16);
}
__device__ __forceinline__ float bf2f(short s) {
  union { unsigned u; float f; } x;
  x.u = ((unsigned)(unsigned short)s) << 16;
  return x.f;
}

// physical index into a swizzled [32][256] bf16 tile (16B chunks XOR-swizzled
// within each 128B block by row&7; matches gemm_tri's As layout)
__device__ __forceinline__ int o1s_phys(int q, int ch) {
  return q * 256 + (ch & ~63) + ((((ch >> 3) & 7) ^ (q & 7)) << 3) + (ch & 7);
}

// stage one 256x64 bf16 W k-block into LDS, gemm_tri swizzle, 16B DMA
__device__ __forceinline__ void stage_w(short* Wsl, const short* Wg, int kb,
                                        int wave, int lane, int rsub, int csub) {
#pragma unroll
  for (int j = 0; j < 8; ++j) {
    int r0 = (wave * 8 + j) * 8;
    int row = r0 + rsub;
    int c = csub ^ (row & 7);
    const short* gp = Wg + (long)row * 256 + kb * 64 + c * 8;
    short* lp = &Wsl[r0 * 64 + lane * 8];
    __builtin_amdgcn_global_load_lds((const GLOBAL_AS void*)gp,
                                     (LDS_AS void*)lp, 16, 0, 0);
  }
}

// stage a full 32x256 bf16 token tile (rows m1 = l1*512 + b1) into swizzled
// LDS: linear dest, pre-swizzled global source (within-128B-block chunk XOR)
__device__ __forceinline__ void stage_tile(short* dst, const short* Xg,
                                           int b1, int tid) {
#pragma unroll
  for (int p = 0; p < 4; ++p) {
    int idx = p * 256 + tid;       // 0..1023
    int row = idx >> 5;            // 0..31
    int ch = idx & 31;             // 16B chunk within row
    int chs = (ch & ~7) | ((ch & 7) ^ (row & 7));
    const short* gp = Xg + ((long)(row * 512 + b1)) * 256 + chs * 8;
    short* lp = dst + idx * 8;
    __builtin_amdgcn_global_load_lds((const GLOBAL_AS void*)gp,
                                     (LDS_AS void*)lp, 16, 0, 0);
  }
}

// ---- pack: [n,c,t,h,w] fp32 -> token-major [16384,256] bf16; + weight cvt --
__global__ __launch_bounds__(256) void pack_kernel(
    const float* __restrict__ q, const float* __restrict__ k,
    const float* __restrict__ v, const float* __restrict__ pos,
    short* __restrict__ Xp, short* __restrict__ Xq,
    short* __restrict__ Xk, short* __restrict__ Xv,
    const float* __restrict__ wl_in, const float* __restrict__ wl_out,
    const float* __restrict__ ws_in, const float* __restrict__ ws_out,
    short* __restrict__ wbf) {
  __shared__ float tP[64][65];
  __shared__ float tX[64][65];
  int b = blockIdx.x;
  int cb = b & 3;
  int h  = (b >> 2) & 63;
  int nt = b >> 8;
  int n = nt >> 1, t = nt & 1;
  int c0 = cb * 64;
  int bh = h >> 4, ii = h & 15;
  long inbase = (long)n * 2097152 + (long)t * 4096 + (long)h * 64;
  int tx = threadIdx.x & 63;
  int ty = threadIdx.x >> 6;  // 0..3

  for (int cc = ty; cc < 64; cc += 4) {
    long a = inbase + (long)(c0 + cc) * 8192 + tx;
    tP[cc][tx] = pos[a];
    tX[cc][tx] = q[a];
  }
  __syncthreads();
  for (int ww = ty; ww < 64; ww += 4) {
    int bw = ww >> 4, j = ww & 15;
    int m1 = (((t * 4 + bh) * 4 + bw) * 512) + n * 256 + ii * 16 + j;
    long o = (long)m1 * 256 + c0 + tx;
    float pv = tP[tx][ww];
    Xp[o] = f2bf(pv);
    Xq[o] = f2bf(tX[tx][ww] + pv);
  }
  __syncthreads();
  for (int cc = ty; cc < 64; cc += 4) {
    long a = inbase + (long)(c0 + cc) * 8192 + tx;
    tX[cc][tx] = k[a];
  }
  __syncthreads();
  for (int ww = ty; ww < 64; ww += 4) {
    int bw = ww >> 4, j = ww & 15;
    int m1 = (((t * 4 + bh) * 4 + bw) * 512) + n * 256 + ii * 16 + j;
    long o = (long)m1 * 256 + c0 + tx;
    Xk[o] = f2bf(tX[tx][ww] + tP[tx][ww]);
  }
  __syncthreads();
  for (int cc = ty; cc < 64; cc += 4) {
    long a = inbase + (long)(c0 + cc) * 8192 + tx;
    tX[cc][tx] = v[a];
  }
  __syncthreads();
  for (int ww = ty; ww < 64; ww += 4) {
    int bw = ww >> 4, j = ww & 15;
    int m1 = (((t * 4 + bh) * 4 + bw) * 512) + n * 256 + ii * 16 + j;
    long o = (long)m1 * 256 + c0 + tx;
    Xv[o] = f2bf(tX[tx][ww]);
  }
  // weight convert tail: 1024 blocks x 256 threads x 2 floats = 524288
  int idx = (blockIdx.x * 256 + threadIdx.x) * 2;
  const float* wp;
  if (idx < 196608) wp = wl_in + idx;
  else if (idx < 262144) wp = wl_out + (idx - 196608);
  else if (idx < 458752) wp = ws_in + (idx - 262144);
  else wp = ws_out + (idx - 458752);
  float2 wv = *(const float2*)wp;
  wbf[idx] = f2bf(wv.x);
  wbf[idx + 1] = f2bf(wv.y);
}

// ------- m97-style bf16 TN GEMM triple: C_z = A_z @ W_z^T + b_z -------------
// Tile 128x64, BK=64, global_load_lds 16B staging, XOR swizzle pc=c^(row&7).
template <bool OUT32>
__global__ __launch_bounds__(256) void gemm_tri(
    const short* __restrict__ A0, const short* __restrict__ A1,
    const short* __restrict__ A2, const short* __restrict__ W0,
    const float* __restrict__ bias0, void* __restrict__ C0,
    void* __restrict__ C1, void* __restrict__ C2) {
  __shared__ short As[128 * 64];  // 16 KB
  __shared__ short Ws[64 * 64];   //  8 KB
  int z = blockIdx.z;
  const short* A = (z == 0) ? A0 : ((z == 1) ? A1 : A2);
  const short* Wb = W0 + z * 65536;
  const float* bias = bias0 + z * 256;
  void* Csel = (z == 0) ? C0 : ((z == 1) ? C1 : C2);
  int m0 = blockIdx.x * 128;
  int n0 = blockIdx.y * 64;
  int tid = threadIdx.x;
  int lane = tid & 63, wave = tid >> 6;
  int wm = wave >> 1, wn = wave & 1;
  int l15 = lane & 15, quad = lane >> 4;
  int x7 = l15 & 7;
  int rsub = lane >> 3;   // 0..7: row within 8-row staging chunk
  int csub = lane & 7;    // logical col16 before swizzle

  floatx4 acc[4][2];
#pragma unroll
  for (int mt = 0; mt < 4; ++mt)
#pragma unroll
    for (int nt = 0; nt < 2; ++nt) acc[mt][nt] = (floatx4)(0.f);

  for (int kb = 0; kb < 4; ++kb) {
    int k0 = kb * 64;
    if (kb) __syncthreads();
#pragma unroll
    for (int j = 0; j < 4; ++j) {
      int r0 = (wave * 4 + j) * 8;
      int row = r0 + rsub;
      int c = csub ^ (row & 7);
      const short* gp = A + (long)(m0 + row) * 256 + k0 + c * 8;
      short* lp = &As[r0 * 64 + lane * 8];
      __builtin_amdgcn_global_load_lds((const GLOBAL_AS void*)gp,
                                       (LDS_AS void*)lp, 16, 0, 0);
    }
#pragma unroll
    for (int j = 0; j < 2; ++j) {
      int r0 = (wave * 2 + j) * 8;
      int row = r0 + rsub;
      int c = csub ^ (row & 7);
      const short* gp = Wb + (long)(n0 + row) * 256 + k0 + c * 8;
      short* lp = &Ws[r0 * 64 + lane * 8];
      __builtin_amdgcn_global_load_lds((const GLOBAL_AS void*)gp,
                                       (LDS_AS void*)lp, 16, 0, 0);
    }
    __syncthreads();
#pragma unroll
    for (int ks = 0; ks < 2; ++ks) {
      int pc = (ks * 4 + quad) ^ x7;
      short8 af[4], bfr[2];
#pragma unroll
      for (int mt = 0; mt < 4; ++mt) {
        int row = wm * 64 + mt * 16 + l15;
        af[mt] = *(const short8*)&As[row * 64 + pc * 8];
      }
#pragma unroll
      for (int nt = 0; nt < 2; ++nt) {
        int row = wn * 32 + nt * 16 + l15;
        bfr[nt] = *(const short8*)&Ws[row * 64 + pc * 8];
      }
#pragma unroll
      for (int mt = 0; mt < 4; ++mt)
#pragma unroll
        for (int nt = 0; nt < 2; ++nt)
          acc[mt][nt] = __builtin_amdgcn_mfma_f32_16x16x32_bf16(
              af[mt], bfr[nt], acc[mt][nt], 0, 0, 0);
    }
  }
  float bia0 = bias[n0 + wn * 32 + l15];
  float bia1 = bias[n0 + wn * 32 + 16 + l15];
#pragma unroll
  for (int mt = 0; mt < 4; ++mt) {
#pragma unroll
    for (int r = 0; r < 4; ++r) {
      int row = m0 + wm * 64 + mt * 16 + quad * 4 + r;
      long base = (long)row * 256 + n0 + wn * 32 + l15;
      if (OUT32) {
        float* C = (float*)Csel;
        C[base] = acc[mt][0][r] + bia0;
        C[base + 16] = acc[mt][1][r] + bia1;
      } else {
        short* C = (short*)Csel;
        C[base] = f2bf(acc[mt][0][r] + bia0);
        C[base + 16] = f2bf(acc[mt][1][r] + bia1);
      }
    }
  }
}

// ---- giga-fused stage-1: in-proj + attn + out-proj + perm + pos + s2-in-proj
// One block (4 waves) per b1. Regions: R1=Xq->Q1->O1s, R2=Xk->K1->X2s,
// R3=Xv->V1->Vins, R4=Ws union (Vt+Pw during attention). 80 KB -> 2 blk/CU.
__global__ __launch_bounds__(256) void attn1_giga(
    const short* __restrict__ Xq, const short* __restrict__ Xk,
    const short* __restrict__ Xv, const short* __restrict__ Xp,
    const short* __restrict__ Wlin, const float* __restrict__ bias_lin,
    const short* __restrict__ Wo, const float* __restrict__ bias_o,
    const short* __restrict__ Wsin, const float* __restrict__ bias_sin,
    short* __restrict__ Q2, short* __restrict__ K2, short* __restrict__ V2) {
  __shared__ short R1[32 * 256];   // 16 KB
  __shared__ short R2[32 * 256];   // 16 KB
  __shared__ short R3[32 * 256];   // 16 KB
  __shared__ short R4[256 * 64];   // 32 KB (Ws; or Vt+Pw during attn)
  int b1 = blockIdx.x;
  int tid = threadIdx.x;
  int wave = tid >> 6, lane = tid & 63;
  int l15 = lane & 15, quad = lane >> 4;
  int x7 = l15 & 7;
  int rsub = lane >> 3;
  int csub = lane & 7;

  floatx4 acc[2][4];

  // ======== phase A: Q1/K1/V1 = Xz @ wl_z^T + b_z, in place ========
#pragma unroll 1
  for (int z = 0; z < 3; ++z) {
    short* Rz = (z == 0) ? R1 : ((z == 1) ? R2 : R3);
    const short* Xg = (z == 0) ? Xq : ((z == 1) ? Xk : Xv);
    const short* Wz = Wlin + z * 65536;
    stage_tile(Rz, Xg, b1, tid);
#pragma unroll
    for (int mt = 0; mt < 2; ++mt)
#pragma unroll
      for (int nt = 0; nt < 4; ++nt) acc[mt][nt] = (floatx4)(0.f);
    for (int kb = 0; kb < 4; ++kb) {
      __syncthreads();   // prior Ws reads done; kb=0: tile DMA drained
      stage_w(R4, Wz, kb, wave, lane, rsub, csub);
      __syncthreads();
#pragma unroll
      for (int ks = 0; ks < 2; ++ks) {
        int pc = (ks * 4 + quad) ^ x7;
        short8 af[2], bfr[4];
#pragma unroll
        for (int mt = 0; mt < 2; ++mt)
          af[mt] = *(const short8*)&Rz[(mt * 16 + l15) * 256 + kb * 64 + pc * 8];
#pragma unroll
        for (int nt = 0; nt < 4; ++nt)
          bfr[nt] = *(const short8*)&R4[(wave * 64 + nt * 16 + l15) * 64 + pc * 8];
#pragma unroll
        for (int mt = 0; mt < 2; ++mt)
#pragma unroll
          for (int nt = 0; nt < 4; ++nt)
            acc[mt][nt] = __builtin_amdgcn_mfma_f32_16x16x32_bf16(
                af[mt], bfr[nt], acc[mt][nt], 0, 0, 0);
      }
    }
    __syncthreads();  // all waves done reading Rz before overwrite
    float bz[4];
#pragma unroll
    for (int nt = 0; nt < 4; ++nt)
      bz[nt] = bias_lin[z * 256 + wave * 64 + nt * 16 + l15];
#pragma unroll
    for (int mt = 0; mt < 2; ++mt)
#pragma unroll
      for (int r = 0; r < 4; ++r) {
        int row = mt * 16 + quad * 4 + r;
#pragma unroll
        for (int nt = 0; nt < 4; ++nt) {
          int col = wave * 64 + nt * 16 + l15;
          Rz[o1s_phys(row, col)] = f2bf(acc[mt][nt][r] + bz[nt]);
        }
      }
  }
  __syncthreads();  // Q1/K1/V1 tiles visible to all waves

  // ======== phase B: attention (R12 math; frags from swizzled LDS) ========
  short* Vtb = R4;           // [4][32][40] shorts = 5120
  short* Pwb = R4 + 5120;    // [4][32][40]
  int key = lane & 31;
  int dh = (lane >> 5) * 16;                 // 0 or 16
  int pc2 = 2 * (key & 15) + (key >> 4);     // pi2(key)

  floatx4 oacc[2][4];    // [h2][o00,o01,o10,o11]
  float lsum[2][2][4];   // [h2][li0/li1][r]

#pragma unroll
  for (int h2 = 0; h2 < 2; ++h2) {
    int hh = wave * 2 + h2;
    int cb0 = hh * 32 + quad * 8;
    short8 qf0 = *(const short8*)&R1[o1s_phys(l15, cb0)];
    short8 qf1 = *(const short8*)&R1[o1s_phys(l15 + 16, cb0)];
    short8 kf0 = *(const short8*)&R2[o1s_phys(l15, cb0)];
    short8 kf1 = *(const short8*)&R2[o1s_phys(l15 + 16, cb0)];
    // V^T for this head: Vt[d][pi2(key)]; lanes 0-31: d 0..15, 32-63: 16..31
    short8 v0 = *(const short8*)&R3[o1s_phys(key, hh * 32 + dh)];
    short8 v1 = *(const short8*)&R3[o1s_phys(key, hh * 32 + dh + 8)];
#pragma unroll
    for (int j = 0; j < 8; ++j) {
      Vtb[(wave * 32 + dh + j) * 40 + pc2] = v0[j];
      Vtb[(wave * 32 + dh + 8 + j) * 40 + pc2] = v1[j];
    }
    // S = Q K^T (4 tiles)
    floatx4 s00 = __builtin_amdgcn_mfma_f32_16x16x32_bf16(qf0, kf0, (floatx4)(0.f), 0, 0, 0);
    floatx4 s01 = __builtin_amdgcn_mfma_f32_16x16x32_bf16(qf0, kf1, (floatx4)(0.f), 0, 0, 0);
    floatx4 s10 = __builtin_amdgcn_mfma_f32_16x16x32_bf16(qf1, kf0, (floatx4)(0.f), 0, 0, 0);
    floatx4 s11 = __builtin_amdgcn_mfma_f32_16x16x32_bf16(qf1, kf1, (floatx4)(0.f), 0, 0, 0);
    // no-max softmax; P[q][pi2(k)]: key tiles j=0,1 -> cols 2*l15, 2*l15+1
    float li0[4], li1[4];
#pragma unroll
    for (int r = 0; r < 4; ++r) {
      float p00 = __builtin_amdgcn_exp2f(s00[r] * EXP2_SCALE);
      float p01 = __builtin_amdgcn_exp2f(s01[r] * EXP2_SCALE);
      float p10 = __builtin_amdgcn_exp2f(s10[r] * EXP2_SCALE);
      float p11 = __builtin_amdgcn_exp2f(s11[r] * EXP2_SCALE);
      li0[r] = p00 + p01;
      li1[r] = p10 + p11;
      short2v pa, pb;
      pa.x = f2bf(p00); pa.y = f2bf(p01);
      pb.x = f2bf(p10); pb.y = f2bf(p11);
      *(short2v*)&Pwb[(wave * 32 + quad * 4 + r) * 40 + 2 * l15] = pa;
      *(short2v*)&Pwb[(wave * 32 + 16 + quad * 4 + r) * 40 + 2 * l15] = pb;
    }
#pragma unroll
    for (int r = 0; r < 4; ++r) {
      li0[r] += __shfl_xor(li0[r], 1, 64);
      li0[r] += __shfl_xor(li0[r], 2, 64);
      li0[r] += __shfl_xor(li0[r], 4, 64);
      li0[r] += __shfl_xor(li0[r], 8, 64);
      li1[r] += __shfl_xor(li1[r], 1, 64);
      li1[r] += __shfl_xor(li1[r], 2, 64);
      li1[r] += __shfl_xor(li1[r], 4, 64);
      li1[r] += __shfl_xor(li1[r], 8, 64);
      lsum[h2][0][r] = li0[r];
      lsum[h2][1][r] = li1[r];
    }
    // PV: O[32q][32d] = P[32q][32k] V[32k][32d] (k pi2-ordered both sides)
    short8 pf0 = *(const short8*)&Pwb[(wave * 32 + l15) * 40 + quad * 8];
    short8 pf1 = *(const short8*)&Pwb[(wave * 32 + 16 + l15) * 40 + quad * 8];
    short8 vt0 = *(const short8*)&Vtb[(wave * 32 + l15) * 40 + quad * 8];
    short8 vt1 = *(const short8*)&Vtb[(wave * 32 + 16 + l15) * 40 + quad * 8];
    oacc[h2][0] = __builtin_amdgcn_mfma_f32_16x16x32_bf16(pf0, vt0, (floatx4)(0.f), 0, 0, 0);
    oacc[h2][1] = __builtin_amdgcn_mfma_f32_16x16x32_bf16(pf0, vt1, (floatx4)(0.f), 0, 0, 0);
    oacc[h2][2] = __builtin_amdgcn_mfma_f32_16x16x32_bf16(pf1, vt0, (floatx4)(0.f), 0, 0, 0);
    oacc[h2][3] = __builtin_amdgcn_mfma_f32_16x16x32_bf16(pf1, vt1, (floatx4)(0.f), 0, 0, 0);
  }

  __syncthreads();  // attn reads done; safe to overwrite R1 with O1s

  // ---- spill normalized O tile (bf16, swizzled) into R1 ----
#pragma unroll
  for (int h2 = 0; h2 < 2; ++h2) {
    int hh = wave * 2 + h2;
    int cA = hh * 32 + l15;
    int cB = cA + 16;
#pragma unroll
    for (int r = 0; r < 4; ++r) {
      float inv0 = 1.f / lsum[h2][0][r];
      float inv1 = 1.f / lsum[h2][1][r];
      int qa = quad * 4 + r, qb = 16 + quad * 4 + r;
      R1[o1s_phys(qa, cA)] = f2bf(oacc[h2][0][r] * inv0);
      R1[o1s_phys(qa, cB)] = f2bf(oacc[h2][1][r] * inv0);
      R1[o1s_phys(qb, cA)] = f2bf(oacc[h2][2][r] * inv1);
      R1[o1s_phys(qb, cB)] = f2bf(oacc[h2][3][r] * inv1);
    }
  }

  // ======== phase C: C1 = O1s @ Wo^T ========
#pragma unroll
  for (int mt = 0; mt < 2; ++mt)
#pragma unroll
    for (int nt = 0; nt < 4; ++nt) acc[mt][nt] = (floatx4)(0.f);
  for (int kb = 0; kb < 4; ++kb) {
    __syncthreads();  // kb=0: spill visible + Vt/Pw reads done; else Ws reads
    stage_w(R4, Wo, kb, wave, lane, rsub, csub);
    __syncthreads();
#pragma unroll
    for (int ks = 0; ks < 2; ++ks) {
      int pc = (ks * 4 + quad) ^ x7;
      short8 af[2], bfr[4];
#pragma unroll
      for (int mt = 0; mt < 2; ++mt)
        af[mt] = *(const short8*)&R1[(mt * 16 + l15) * 256 + kb * 64 + pc * 8];
#pragma unroll
      for (int nt = 0; nt < 4; ++nt)
        bfr[nt] = *(const short8*)&R4[(wave * 64 + nt * 16 + l15) * 64 + pc * 8];
#pragma unroll
      for (int mt = 0; mt < 2; ++mt)
#pragma unroll
        for (int nt = 0; nt < 4; ++nt)
          acc[mt][nt] = __builtin_amdgcn_mfma_f32_16x16x32_bf16(
              af[mt], bfr[nt], acc[mt][nt], 0, 0, 0);
    }
  }

  __syncthreads();
  // ---- X2s (=C1+b+pos) -> R2, Vins (=C1+b) -> R3, both swizzled ----
  {
    float bvo[4];
#pragma unroll
    for (int nt = 0; nt < 4; ++nt) bvo[nt] = bias_o[wave * 64 + nt * 16 + l15];
#pragma unroll
    for (int mt = 0; mt < 2; ++mt) {
#pragma unroll
      for (int r = 0; r < 4; ++r) {
        int qrow = mt * 16 + quad * 4 + r;
        long pbase = ((long)qrow * 512 + b1) * 256;
#pragma unroll
        for (int nt = 0; nt < 4; ++nt) {
          int col = wave * 64 + nt * 16 + l15;
          float val = acc[mt][nt][r] + bvo[nt];
          int ph = o1s_phys(qrow, col);
          R3[ph] = f2bf(val);
          R2[ph] = f2bf(val + bf2f(Xp[pbase + col]));  // X2s
        }
      }
    }
  }

  // ======== phase D: Q2/K2/V2 = {X2s,X2s,Vins} @ ws_{q,k,v}^T + b ========
  int nn = b1 >> 8, ii = (b1 >> 4) & 15, jj = b1 & 15;
#pragma unroll 1
  for (int z = 0; z < 3; ++z) {
    const short* Wz = Wsin + z * 65536;
    const short* Ab = (z < 2) ? R2 : R3;
    short* outz = (z == 0) ? Q2 : ((z == 1) ? K2 : V2);
    float bz[4];
#pragma unroll
    for (int nt = 0; nt < 4; ++nt)
      bz[nt] = bias_sin[z * 256 + wave * 64 + nt * 16 + l15];
#pragma unroll
    for (int mt = 0; mt < 2; ++mt)
#pragma unroll
      for (int nt = 0; nt < 4; ++nt) acc[mt][nt] = (floatx4)(0.f);
    for (int kb = 0; kb < 4; ++kb) {
      __syncthreads();  // z0/kb0: X2s/Vins visible; else prior Ws reads done
      stage_w(R4, Wz, kb, wave, lane, rsub, csub);
      __syncthreads();
#pragma unroll
      for (int ks = 0; ks < 2; ++ks) {
        int pc = (ks * 4 + quad) ^ x7;
        short8 af[2], bfr[4];
#pragma unroll
        for (int mt = 0; mt < 2; ++mt)
          af[mt] = *(const short8*)&Ab[(mt * 16 + l15) * 256 + kb * 64 + pc * 8];
#pragma unroll
        for (int nt = 0; nt < 4; ++nt)
          bfr[nt] = *(const short8*)&R4[(wave * 64 + nt * 16 + l15) * 64 + pc * 8];
#pragma unroll
        for (int mt = 0; mt < 2; ++mt)
#pragma unroll
          for (int nt = 0; nt < 4; ++nt)
            acc[mt][nt] = __builtin_amdgcn_mfma_f32_16x16x32_bf16(
                af[mt], bfr[nt], acc[mt][nt], 0, 0, 0);
      }
    }
    // epilogue: +bias, m1->m2 perm, store
#pragma unroll
    for (int mt = 0; mt < 2; ++mt) {
#pragma unroll
      for (int r = 0; r < 4; ++r) {
        int qrow = mt * 16 + quad * 4 + r;
        int t = qrow >> 4, bh = (qrow >> 2) & 3, bw = qrow & 3;
        int m2 = (t * 256 + ii * 16 + jj) * 32 + nn * 16 + bh * 4 + bw;
        long xbase = (long)m2 * 256;
#pragma unroll
        for (int nt = 0; nt < 4; ++nt) {
          int col = wave * 64 + nt * 16 + l15;
          outz[xbase + col] = f2bf(acc[mt][nt][r] + bz[nt]);
        }
      }
    }
  }
}

// ---------------- stage-2 attention: MFMA flash, no-max softmax -------------
// R6 staging (LDS K + pi-V^T, 2 barriers/chunk) + exp2 no-max softmax.
// grid 2048: bid = qblk*256 + rest, rest = (hh&1)*128 + b2*4 + (hh>>1).
__global__ __launch_bounds__(256) void attn2_mfma(
    const short* __restrict__ Q2, const short* __restrict__ K2,
    const short* __restrict__ V2, short* __restrict__ O2) {
  __shared__ short Ks[64][40];      // [key][d]
  __shared__ short Vt[32][72];      // [d][pi(key)]
  __shared__ short Pw[4][16][72];   // per-wave P [q][pi(key)]
  int bid = blockIdx.x;
  int rest = bid & 255;
  int qblk = bid >> 8;
  int hh = 2 * (rest & 3) + (rest >> 7);
  int b2 = (rest >> 2) & 31;
  int tid = threadIdx.x;
  int wave = tid >> 6, lane = tid & 63;
  int l15 = lane & 15, quad = lane >> 4;

  short8 qf;
  {
    long tok = (long)(qblk * 64 + wave * 16 + l15) * 32 + b2;
    qf = *(const short8*)(Q2 + tok * 256 + hh * 32 + quad * 8);
  }
  floatx4 Oa = (floatx4)(0.f), Ob = (floatx4)(0.f);
  float li[4] = {0.f, 0.f, 0.f, 0.f};

  int skey = tid >> 2;          // K staging: 0..63
  int sd0 = (tid & 3) * 8;
  int vkey = lane;              // V staging
  int vd0 = wave * 8;
  int vcol = (vkey & 15) * 4 + (vkey >> 4);  // pi(key)

  for (int kb = 0; kb < 8; ++kb) {
    if (kb) __syncthreads();
    {  // stage K [64][32] bf16 passthrough
      long tok = (long)(kb * 64 + skey) * 32 + b2;
      *(short8*)&Ks[skey][sd0] = *(const short8*)(K2 + tok * 256 + hh * 32 + sd0);
    }
    {  // stage V^T [32][pi(64)] bf16 passthrough
      long tok = (long)(kb * 64 + vkey) * 32 + b2;
      short8 v = *(const short8*)(V2 + tok * 256 + hh * 32 + vd0);
#pragma unroll
      for (int j = 0; j < 8; ++j) Vt[vd0 + j][vcol] = v[j];
    }
    __syncthreads();
    floatx4 st[4];
#pragma unroll
    for (int kt = 0; kt < 4; ++kt) {
      short8 kf = *(const short8*)&Ks[kt * 16 + l15][quad * 8];
      st[kt] = __builtin_amdgcn_mfma_f32_16x16x32_bf16(qf, kf, (floatx4)(0.f), 0, 0, 0);
    }
#pragma unroll
    for (int r = 0; r < 4; ++r) {
      float p0 = __builtin_amdgcn_exp2f(st[0][r] * EXP2_SCALE);
      float p1 = __builtin_amdgcn_exp2f(st[1][r] * EXP2_SCALE);
      float p2 = __builtin_amdgcn_exp2f(st[2][r] * EXP2_SCALE);
      float p3 = __builtin_amdgcn_exp2f(st[3][r] * EXP2_SCALE);
      li[r] += (p0 + p1) + (p2 + p3);
      short4v pp;
      pp.x = f2bf(p0); pp.y = f2bf(p1); pp.z = f2bf(p2); pp.w = f2bf(p3);
      *(short4v*)&Pw[wave][quad * 4 + r][l15 * 4] = pp;
    }
#pragma unroll
    for (int kk = 0; kk < 2; ++kk) {
      short8 pf = *(const short8*)&Pw[wave][l15][kk * 32 + quad * 8];
      short8 v0 = *(const short8*)&Vt[l15][kk * 32 + quad * 8];
      short8 v1 = *(const short8*)&Vt[16 + l15][kk * 32 + quad * 8];
      Oa = __builtin_amdgcn_mfma_f32_16x16x32_bf16(pf, v0, Oa, 0, 0, 0);
      Ob = __builtin_amdgcn_mfma_f32_16x16x32_bf16(pf, v1, Ob, 0, 0, 0);
    }
  }
#pragma unroll
  for (int r = 0; r < 4; ++r) {
    float s = li[r];
    s += __shfl_xor(s, 1, 64);
    s += __shfl_xor(s, 2, 64);
    s += __shfl_xor(s, 4, 64);
    s += __shfl_xor(s, 8, 64);
    float inv = 1.f / s;
    long tok = (long)(qblk * 64 + wave * 16 + quad * 4 + r) * 32 + b2;
    long a = tok * 256 + hh * 32 + l15;
    O2[a] = f2bf(Oa[r] * inv);
    O2[a + 16] = f2bf(Ob[r] * inv);
  }
}

// ---------------- unpack: [16384,256] fp32 (m2-order) -> out [n,c,t,h,w] ----
__global__ __launch_bounds__(256) void unpack_kernel(
    const float* __restrict__ Y, float* __restrict__ out) {
  __shared__ float tl[64][65];
  int b = blockIdx.x;
  int cb = b & 3;
  int h = (b >> 2) & 63;
  int nt = b >> 8;
  int n = nt >> 1, t = nt & 1;
  int c0 = cb * 64;
  int bh = h >> 4, ii = h & 15;
  int tx = threadIdx.x & 63;
  int ty = threadIdx.x >> 6;
  for (int ww = ty; ww < 64; ww += 4) {
    int bw = ww >> 4, j = ww & 15;
    int l2 = t * 256 + ii * 16 + j;
    int b2 = n * 16 + bh * 4 + bw;
    int m2 = l2 * 32 + b2;
    tl[tx][ww] = Y[(long)m2 * 256 + c0 + tx];
  }
  __syncthreads();
  long ob = (long)n * 2097152 + (long)t * 4096 + (long)h * 64 + tx;
  for (int cc = ty; cc < 64; cc += 4) {
    out[ob + (long)(c0 + cc) * 8192] = tl[cc][tx];
  }
}

extern "C" void kernel_launch(void* const* d_in, const int* in_sizes, int n_in,
                              void* d_out, int out_size, void* d_ws, size_t ws_size,
                              hipStream_t stream) {
  const float* q      = (const float*)d_in[0];
  const float* k      = (const float*)d_in[1];
  const float* v      = (const float*)d_in[2];
  const float* pos    = (const float*)d_in[3];
  const float* wl_in  = (const float*)d_in[4];
  const float* bl_in  = (const float*)d_in[5];
  const float* wl_out = (const float*)d_in[6];
  const float* bl_out = (const float*)d_in[7];
  const float* ws_in  = (const float*)d_in[8];
  const float* bs_in  = (const float*)d_in[9];
  const float* ws_out = (const float*)d_in[10];
  const float* bs_out = (const float*)d_in[11];
  float* out = (float*)d_out;
  char* wsb = (char*)d_ws;
  const size_t SLB = 16777216;  // 16 MB per slot (bf16 tensors use half)
  short* s0 = (short*)(wsb);            // Xp (8 MB)
  short* wbf = (short*)(wsb + SLB / 2); // bf16 weights (1 MB)
  short* s1 = (short*)(wsb + SLB);      // Xq -> O2
  short* s2 = (short*)(wsb + 2 * SLB);  // Xk -> Yfinal(fp32)
  short* s3 = (short*)(wsb + 3 * SLB);  // Xv
  short* s4 = (short*)(wsb + 4 * SLB);  // Q2
  short* s5 = (short*)(wsb + 5 * SLB);  // K2
  short* s6 = (short*)(wsb + 6 * SLB);  // V2

  pack_kernel<<<1024, 256, 0, stream>>>(q, k, v, pos, s0, s1, s2, s3,
                                        wl_in, wl_out, ws_in, ws_out, wbf);

  // giga-fused stage-1 (in-proj + attn + out-proj + perm + pos + s2 in-proj):
  // Q2 -> s4, K2 -> s5, V2 -> s6
  attn1_giga<<<512, 256, 0, stream>>>(s1, s2, s3, s0, wbf, bl_in,
                                      wbf + 196608, bl_out,
                                      wbf + 262144, bs_in, s4, s5, s6);

  attn2_mfma<<<2048, 256, 0, stream>>>(s4, s5, s6, s1);   // O2 -> s1
  // Yfinal (fp32) = O2 @ ws_out^T
  dim3 g1(128, 4, 1);
  gemm_tri<true><<<g1, 256, 0, stream>>>(s1, s1, s1, wbf + 458752, bs_out,
                                         s2, s2, s2);

  unpack_kernel<<<1024, 256, 0, stream>>>((const float*)s2, out);
}